// Round 7
// baseline (997.464 us; speedup 1.0000x reference)
//
#include <hip/hip_runtime.h>

// Shapes (fixed):
//   prev/next: [8, 32, 48, 48, 48] f32
//   phi:       [8, 1, 96, 96, 96] f32
//   stream:    [8, 3, 96, 96, 96] f32
// Outputs concatenated in d_out (f32): corr [8,27,48^3], vel/vel_phi/vel_stream [8,3,94^3]
//
// R7 theory: wall is vector-memory INSTRUCTION throughput (~24 cy/wave-instr,
// calibrated from R3), insensitive to bytes/occupancy/stores. Fix: move the
// stencil reuse onto the LDS pipe (parallel to TA). corr: stage 3 nxt planes
// per c (4 global loads/c vs 10). vel: stage 4-volume tile+halo, 4 t-outputs
// per thread (16 vmem per 4 sites vs 45 per 2). nt stores kept (R5: nt > normal).

typedef float f2 __attribute__((ext_vector_type(2)));
typedef float f4 __attribute__((ext_vector_type(4)));
typedef float f4u __attribute__((ext_vector_type(4), aligned(8)));

constexpr int CB = 8, CC = 32, CX = 48, CY = 48, CZ = 48;
constexpr int H = 96, O = 94;
constexpr int PLANE = CY * CZ;       // 2304
constexpr int CSTR  = CX * PLANE;    // 110592
constexpr int HP    = H * H;         // 9216
constexpr size_t HC = (size_t)H * HP;
constexpr size_t O3 = (size_t)O * O * O;

// ---------------------------------------------------------------------------
// corr: block = 576 threads <-> one (b, x). LDS holds 3 nxt x-planes (x-1..x+1)
// with zero halo rows (reference zero-pad semantics). Per c: 3 staged f4 loads
// + 1 prev f4 per thread; 9 taps from LDS. 384 blocks, batch-per-XCD swizzle.
// ---------------------------------------------------------------------------
__global__ __launch_bounds__(576) void corr_kernel(
    const float* __restrict__ prev, const float* __restrict__ nxt,
    float* __restrict__ corr)
{
    __shared__ __align__(16) float lds[3][50][48];   // 28.8 KB
    int bid = blockIdx.x;
    int swz = (bid & 7) * 48 + (bid >> 3);           // XCD k -> batch b = k
    int b = swz / 48, x = swz % 48;
    int tid = (int)threadIdx.x;
    int y = tid / 12, z4 = tid % 12;

    const size_t bbase = (size_t)b * CC * CSTR;
    const float* pb = prev + bbase;
    const float* nb = nxt + bbase;

    if (tid < 288) {                 // zero halo rows 0 and 49 of all 3 planes
        int a = tid / 96, rsel = (tid % 96) / 48, z = tid % 48;
        lds[a][rsel * 49][z] = 0.f;
    }

    const float* nsrc[3]; bool okx[3];
#pragma unroll
    for (int s = 0; s < 3; ++s) {
        int xx = x - 1 + s;
        okx[s] = (unsigned)xx < (unsigned)CX;
        nsrc[s] = nb + (size_t)(okx[s] ? xx : x) * PLANE + (size_t)y * CZ + z4 * 4;
    }
    const float* psrc = pb + (size_t)x * PLANE + (size_t)y * CZ + z4 * 4;

    f4 acc[9];
#pragma unroll
    for (int j = 0; j < 9; ++j) acc[j] = f4{0.f, 0.f, 0.f, 0.f};

    for (int c = 0; c < CC; ++c) {
        __syncthreads();             // protect previous iteration's reads (and init)
#pragma unroll
        for (int s = 0; s < 3; ++s) {
            f4 v = f4{0.f, 0.f, 0.f, 0.f};
            if (okx[s]) v = *reinterpret_cast<const f4*>(nsrc[s]);   // uniform branch
            *reinterpret_cast<f4*>(&lds[s][y + 1][z4 * 4]) = v;
            nsrc[s] += CSTR;
        }
        f4 pv = *reinterpret_cast<const f4*>(psrc);
        psrc += CSTR;
        __syncthreads();
#pragma unroll
        for (int a = 0; a < 3; ++a)
#pragma unroll
            for (int d = 0; d < 3; ++d)
                acc[a * 3 + d] += pv * *reinterpret_cast<const f4*>(&lds[a][y + d][z4 * 4]);
    }

    const float s = 1.0f / 32.0f;
    float* ob = corr + (size_t)b * 27 * CSTR + (size_t)x * PLANE + (size_t)y * CZ + z4 * 4;
#pragma unroll
    for (int jj = 0; jj < 9; ++jj) {
        f4 v = acc[jj] * s;
        f4 gm = v; if (z4 == 11) gm.w = 0.f;         // k=-1: zero z==47
        f4 gp = v; if (z4 == 0)  gp.x = 0.f;         // k=+1: zero z==0
        __builtin_nontemporal_store(gm, (f4*)(ob + (size_t)jj * CSTR));
        __builtin_nontemporal_store(v,  (f4*)(ob + (size_t)(9 + jj) * CSTR));
        __builtin_nontemporal_store(gp, (f4*)(ob + (size_t)(18 + jj) * CSTR));
    }
}

// ---------------------------------------------------------------------------
// vel: block = 256 threads <-> tile (8 i) x (8 j) x (16 t). Stage 4 volumes'
// tile+halo (10x10x18, row padded to 20) in LDS; thread owns 4 t-outputs.
// 6912 blocks (= 864 per batch), batch-per-XCD swizzle.
// ---------------------------------------------------------------------------
struct W6 { f4 a; f2 b; };
__device__ __forceinline__ float wat(const W6& w, int k) {   // k unroll-const
    return k < 4 ? w.a[k] : w.b[k - 4];
}

__global__ __launch_bounds__(256) void vel_kernel(
    const float* __restrict__ phi, const float* __restrict__ stm,
    float* __restrict__ vel, float* __restrict__ vphi, float* __restrict__ vstr)
{
    __shared__ __align__(16) float lds[4][10][10][20];   // 32 KB
    int bid = blockIdx.x;
    int swz = (bid & 7) * 864 + (bid >> 3);              // XCD k -> batch b = k
    int b   = swz / 864;
    int rem = swz % 864;
    int it = rem / 72;            // 0..11
    int jt = (rem / 6) % 12;      // 0..11
    int tt = rem % 6;             // 0..5
    int i0 = it * 8, j0 = jt * 8, t0 = tt * 16;
    const bool lastT = (t0 == 80);

    const float* vb1 = stm + (size_t)b * 3 * HC;
    const float* vbase[4] = { phi + (size_t)b * HC, vb1, vb1 + HC, vb1 + 2 * HC };

    int tid = (int)threadIdx.x;
    // staging: 1600 f4 pieces (rows of 16) + 400 f2 pieces (floats 16..17)
#pragma unroll
    for (int k = 0; k < 8; ++k) {
        int p = tid + k * 256;
        if (p < 1600) {
            int row = p >> 2, piece = p & 3;
            int vol = row / 100, rr = row % 100;
            int di = rr / 10, dj = rr % 10;
            int ii = min(i0 + di, 95), jj = min(j0 + dj, 95);
            const float* src = vbase[vol] + (size_t)ii * HP + (size_t)jj * H + t0 + piece * 4;
            *reinterpret_cast<f4*>(&lds[vol][di][dj][piece * 4]) =
                *reinterpret_cast<const f4*>(src);
        } else if (p < 2000) {
            int row = p - 1600;
            int vol = row / 100, rr = row % 100;
            int di = rr / 10, dj = rr % 10;
            int ii = min(i0 + di, 95), jj = min(j0 + dj, 95);
            f2 v = f2{0.f, 0.f};
            if (!lastT)     // t0+16..17 valid only when t0 < 80
                v = *reinterpret_cast<const f2*>(
                    vbase[vol] + (size_t)ii * HP + (size_t)jj * H + t0 + 16);
            *reinterpret_cast<f2*>(&lds[vol][di][dj][16]) = v;
        }
    }
    __syncthreads();

    int di = tid >> 5, dj = (tid >> 2) & 7, q = tid & 3;
    int tl = 4 * q, t = t0 + tl;

    auto w6 = [&](int vol, int I, int J) -> W6 {
        W6 w;
        w.a = *reinterpret_cast<const f4*>(&lds[vol][I][J][tl]);
        w.b = *reinterpret_cast<const f2*>(&lds[vol][I][J][tl + 4]);
        return w;
    };

    // ---- phi ----
    W6 c11 = w6(0, di + 1, dj + 1);
    W6 r12 = w6(0, di + 1, dj + 2);
    W6 r10 = w6(0, di + 1, dj);
    W6 r21 = w6(0, di + 2, dj + 1);
    W6 r01 = w6(0, di,     dj + 1);
    float mup[4], mvp[4], mwp[4];
#pragma unroll
    for (int o = 0; o < 4; ++o) {
        float pc = wat(c11, o + 1);
        mup[o] = ((wat(c11, o + 2) - pc) + (pc - wat(c11, o))) * 0.5f;
        mvp[o] = ((wat(r12, o + 1) - pc) + (pc - wat(r10, o + 1))) * 0.5f;
        mwp[o] = ((wat(r21, o + 1) - pc) + (pc - wat(r01, o + 1))) * 0.5f;
    }

    // ---- u = d_x s1 - d_y s0 ----
    W6 a1_21 = w6(2, di + 2, dj + 1);
    W6 a1_11 = w6(2, di + 1, dj + 1);
    W6 a0_12 = w6(1, di + 1, dj + 2);
    W6 a0_11 = w6(1, di + 1, dj + 1);
    float u[5];
#pragma unroll
    for (int k = 0; k < 5; ++k)
        u[k] = (wat(a1_21, k) - wat(a1_11, k)) - (wat(a0_12, k) - wat(a0_11, k));
    float mus[4];
#pragma unroll
    for (int o = 0; o < 4; ++o) mus[o] = (u[o + 1] + u[o]) * 0.5f;

    // ---- v = d_t s0 - d_x s2 ----
    W6 a0_10 = w6(1, di + 1, dj);
    W6 a2_21 = w6(3, di + 2, dj + 1);
    W6 a2_11 = w6(3, di + 1, dj + 1);
    W6 a2_20 = w6(3, di + 2, dj);
    W6 a2_10 = w6(3, di + 1, dj);
    float mvs[4];
#pragma unroll
    for (int o = 0; o < 4; ++o) {
        float v1 = (wat(a0_11, o + 2) - wat(a0_11, o + 1)) - (wat(a2_21, o + 1) - wat(a2_11, o + 1));
        float v0 = (wat(a0_10, o + 2) - wat(a0_10, o + 1)) - (wat(a2_20, o + 1) - wat(a2_10, o + 1));
        mvs[o] = (v1 + v0) * 0.5f;
    }

    // ---- w = d_y s2 - d_t s1 ----
    W6 a2_12 = w6(3, di + 1, dj + 2);
    W6 a2_02 = w6(3, di,     dj + 2);
    W6 a2_01 = w6(3, di,     dj + 1);
    W6 a1_01 = w6(2, di,     dj + 1);
    float mws[4];
#pragma unroll
    for (int o = 0; o < 4; ++o) {
        float w1 = (wat(a2_12, o + 1) - wat(a2_11, o + 1)) - (wat(a1_11, o + 2) - wat(a1_11, o + 1));
        float w0 = (wat(a2_02, o + 1) - wat(a2_01, o + 1)) - (wat(a1_01, o + 2) - wat(a1_01, o + 1));
        mws[o] = (w1 + w0) * 0.5f;
    }

    // ---- stores ----
    int gi = i0 + di, gj = j0 + dj;
    if (gi <= 93 && gj <= 93) {
        size_t oo = ((size_t)gi * O + gj) * O + t;
        size_t b3 = (size_t)b * 3;
        if (t + 3 <= 93) {
            __builtin_nontemporal_store(f4u{mup[0], mup[1], mup[2], mup[3]}, (f4u*)(vphi + (b3 + 0) * O3 + oo));
            __builtin_nontemporal_store(f4u{mvp[0], mvp[1], mvp[2], mvp[3]}, (f4u*)(vphi + (b3 + 1) * O3 + oo));
            __builtin_nontemporal_store(f4u{mwp[0], mwp[1], mwp[2], mwp[3]}, (f4u*)(vphi + (b3 + 2) * O3 + oo));
            __builtin_nontemporal_store(f4u{mus[0], mus[1], mus[2], mus[3]}, (f4u*)(vstr + (b3 + 0) * O3 + oo));
            __builtin_nontemporal_store(f4u{mvs[0], mvs[1], mvs[2], mvs[3]}, (f4u*)(vstr + (b3 + 1) * O3 + oo));
            __builtin_nontemporal_store(f4u{mws[0], mws[1], mws[2], mws[3]}, (f4u*)(vstr + (b3 + 2) * O3 + oo));
            __builtin_nontemporal_store(f4u{mup[0] + mus[0], mup[1] + mus[1], mup[2] + mus[2], mup[3] + mus[3]}, (f4u*)(vel + (b3 + 0) * O3 + oo));
            __builtin_nontemporal_store(f4u{mvp[0] + mvs[0], mvp[1] + mvs[1], mvp[2] + mvs[2], mvp[3] + mvs[3]}, (f4u*)(vel + (b3 + 1) * O3 + oo));
            __builtin_nontemporal_store(f4u{mwp[0] + mws[0], mwp[1] + mws[1], mwp[2] + mws[2], mwp[3] + mws[3]}, (f4u*)(vel + (b3 + 2) * O3 + oo));
        } else if (t <= 93) {   // t == 92: last two valid
            __builtin_nontemporal_store(f2{mup[0], mup[1]}, (f2*)(vphi + (b3 + 0) * O3 + oo));
            __builtin_nontemporal_store(f2{mvp[0], mvp[1]}, (f2*)(vphi + (b3 + 1) * O3 + oo));
            __builtin_nontemporal_store(f2{mwp[0], mwp[1]}, (f2*)(vphi + (b3 + 2) * O3 + oo));
            __builtin_nontemporal_store(f2{mus[0], mus[1]}, (f2*)(vstr + (b3 + 0) * O3 + oo));
            __builtin_nontemporal_store(f2{mvs[0], mvs[1]}, (f2*)(vstr + (b3 + 1) * O3 + oo));
            __builtin_nontemporal_store(f2{mws[0], mws[1]}, (f2*)(vstr + (b3 + 2) * O3 + oo));
            __builtin_nontemporal_store(f2{mup[0] + mus[0], mup[1] + mus[1]}, (f2*)(vel + (b3 + 0) * O3 + oo));
            __builtin_nontemporal_store(f2{mvp[0] + mvs[0], mvp[1] + mvs[1]}, (f2*)(vel + (b3 + 1) * O3 + oo));
            __builtin_nontemporal_store(f2{mwp[0] + mws[0], mwp[1] + mws[1]}, (f2*)(vel + (b3 + 2) * O3 + oo));
        }
    }
}

extern "C" void kernel_launch(void* const* d_in, const int* in_sizes, int n_in,
                              void* d_out, int out_size, void* d_ws, size_t ws_size,
                              hipStream_t stream)
{
    const float* prev = (const float*)d_in[0];
    const float* nxt  = (const float*)d_in[1];
    const float* phi  = (const float*)d_in[2];
    const float* stm  = (const float*)d_in[3];

    float* out = (float*)d_out;
    const size_t corr_sz = (size_t)CB * 27 * CX * CY * CZ;   // 23,887,872
    const size_t vel_sz  = (size_t)CB * 3 * O * O * O;       // 19,934,016
    float* corr = out;
    float* vel  = out + corr_sz;
    float* vphi = vel + vel_sz;
    float* vstr = vphi + vel_sz;

    corr_kernel<<<384, 576, 0, stream>>>(prev, nxt, corr);
    vel_kernel<<<6912, 256, 0, stream>>>(phi, stm, vel, vphi, vstr);
}

// Round 8
// 171.380 us; speedup vs baseline: 5.8202x; 5.8202x over previous
//
#include <hip/hip_runtime.h>

// Shapes (fixed):
//   prev/next: [8, 32, 48, 48, 48] f32
//   phi:       [8, 1, 96, 96, 96] f32
//   stream:    [8, 3, 96, 96, 96] f32
// Outputs concatenated in d_out (f32): corr [8,27,48^3], vel/vel_phi/vel_stream [8,3,94^3]
//
// R8: base = R3 (best wall 208.7us). ONE change: corr f2 -> f4 (z-granule 4),
// halving corr's vmem instruction count at identical bytes/lines and with
// parallelism preserved (864 corr blocks + 12978 vel blocks in one fused
// launch; vel backfills CUs). Clean A/B: instr-cost vs line-cost model.

typedef float f2 __attribute__((ext_vector_type(2)));
typedef float f4 __attribute__((ext_vector_type(4)));

constexpr int CB = 8, CC = 32, CX = 48, CY = 48, CZ = 48;
constexpr int H = 96, O = 94;
constexpr int PLANE = CY * CZ;       // 2304
constexpr int CSTR  = CX * PLANE;    // 110592

constexpr int CORR_NWG = (CB * CX * CY * (CZ / 4)) / 256;    // 864
constexpr int VEL_TOTAL = CB * O * O * (O / 2);              // 3,322,336
constexpr int VEL_NWG = (VEL_TOTAL + 255) / 256;             // 12978

__device__ __forceinline__ void corr_body(
    int bid, const float* __restrict__ prev, const float* __restrict__ nxt,
    float* __restrict__ corr)
{
    constexpr int Z4 = CZ / 4;                       // 12
    int swz = (bid & 7) * (CORR_NWG / 8) + (bid >> 3);  // XCD-chunked (864%8==0)
    int idx = swz * 256 + (int)threadIdx.x;
    int z4 = idx % Z4; int r = idx / Z4;
    int y = r % CY; r /= CY;
    int x = r % CX; int b = r / CX;

    const size_t bbase = (size_t)b * CC * CSTR;
    const float* __restrict__ nbase = nxt + bbase;

    const float* pp = prev + bbase + (size_t)x * PLANE + (size_t)y * CZ + z4 * 4;

    const float* tp[9];
    float scj[9];
#pragma unroll
    for (int a = 0; a < 3; ++a) {
        int xx = x + a - 1;
        bool vx = (unsigned)xx < (unsigned)CX;
#pragma unroll
        for (int d = 0; d < 3; ++d) {
            int yy = y + d - 1;
            bool ok = vx && ((unsigned)yy < (unsigned)CY);
            // invalid taps read a safe clamped address; zeroed by scj at the end
            tp[a * 3 + d] = nbase + (size_t)(ok ? xx : x) * PLANE
                                  + (size_t)(ok ? yy : y) * CZ + z4 * 4;
            scj[a * 3 + d] = ok ? (1.0f / 32.0f) : 0.0f;
        }
    }

    f4 acc[9];
#pragma unroll
    for (int jj = 0; jj < 9; ++jj) acc[jj] = f4{0.f, 0.f, 0.f, 0.f};

#pragma unroll 2
    for (int c = 0; c < CC; ++c) {
        f4 pv = *reinterpret_cast<const f4*>(pp);
#pragma unroll
        for (int jj = 0; jj < 9; ++jj) {
            f4 nv = *reinterpret_cast<const f4*>(tp[jj]);
            acc[jj] += pv * nv;
            tp[jj] += CSTR;
        }
        pp += CSTR;
    }

    const size_t obase = (size_t)b * 27 * CSTR + (size_t)x * PLANE
                       + (size_t)y * CZ + z4 * 4;
#pragma unroll
    for (int jj = 0; jj < 9; ++jj) {
        f4 v = acc[jj] * scj[jj];
        f4 gm = v; if (z4 == Z4 - 1) gm.w = 0.f;     // k=-1: zero z==47
        f4 gp = v; if (z4 == 0)      gp.x = 0.f;     // k=+1: zero z==0
        __builtin_nontemporal_store(gm, (f4*)(corr + obase + (size_t)jj * CSTR));
        __builtin_nontemporal_store(v,  (f4*)(corr + obase + (size_t)(9 + jj) * CSTR));
        __builtin_nontemporal_store(gp, (f4*)(corr + obase + (size_t)(18 + jj) * CSTR));
    }
}

__device__ __forceinline__ void vel_body(
    int bid, const float* __restrict__ phi, const float* __restrict__ stm,
    float* __restrict__ vel, float* __restrict__ vphi, float* __restrict__ vstr)
{
    constexpr int TT = O / 2;                        // 47
    const int q = VEL_NWG >> 3, rr = VEL_NWG & 7;    // 1622, 2
    int xcd = bid & 7, g = bid >> 3;
    int swz = (xcd < rr) ? (xcd * (q + 1) + g) : (rr * (q + 1) + (xcd - rr) * q + g);
    int idx = swz * 256 + (int)threadIdx.x;
    if (idx >= VEL_TOTAL) return;
    int tt = idx % TT; int r2 = idx / TT;
    int j = r2 % O; r2 /= O;
    int i = r2 % O; int b = r2 / O;
    const int t = tt * 2;

    const int hp = H * H;                            // 9216
    const size_t hc = (size_t)H * hp;
    const float* ph = phi + (size_t)b * hc;
    const float* s0 = stm + (size_t)b * 3 * hc;
    const float* s1 = s0 + hc;
    const float* s2 = s1 + hc;

#define R(A, B_) ((size_t)(A) * hp + (size_t)(B_) * H + t)

    // ---- phi taps ----
    const float* p11 = ph + R(i + 1, j + 1);
    f2 p11a = *(const f2*)p11;           // t, t+1
    f2 p11b = *(const f2*)(p11 + 2);     // t+2, t+3
    float p12_1 = ph[R(i + 1, j + 2) + 1], p12_2 = ph[R(i + 1, j + 2) + 2];
    float p10_1 = ph[R(i + 1, j)     + 1], p10_2 = ph[R(i + 1, j)     + 2];
    float p21_1 = ph[R(i + 2, j + 1) + 1], p21_2 = ph[R(i + 2, j + 1) + 2];
    float p01_1 = ph[R(i,     j + 1) + 1], p01_2 = ph[R(i,     j + 1) + 2];

    float pc0 = p11a.y, pc1 = p11b.x;
    float mup0 = ((p11b.x - pc0) + (pc0 - p11a.x)) * 0.5f;
    float mup1 = ((p11b.y - pc1) + (pc1 - p11a.y)) * 0.5f;
    float mvp0 = ((p12_1 - pc0) + (pc0 - p10_1)) * 0.5f;
    float mvp1 = ((p12_2 - pc1) + (pc1 - p10_2)) * 0.5f;
    float mwp0 = ((p21_1 - pc0) + (pc0 - p01_1)) * 0.5f;
    float mwp1 = ((p21_2 - pc1) + (pc1 - p01_2)) * 0.5f;

    // ---- stream taps ----
    const float* q1_11 = s1 + R(i + 1, j + 1);
    f2 s1_11a = *(const f2*)q1_11;  f2 s1_11b = *(const f2*)(q1_11 + 2);
    const float* q1_21 = s1 + R(i + 2, j + 1);
    f2 s1_21a = *(const f2*)q1_21;  float s1_21_2 = q1_21[2];
    const float* q1_01 = s1 + R(i, j + 1);
    float s1_01_1 = q1_01[1];       f2 s1_01b = *(const f2*)(q1_01 + 2);

    const float* q0_11 = s0 + R(i + 1, j + 1);
    f2 s0_11a = *(const f2*)q0_11;  f2 s0_11b = *(const f2*)(q0_11 + 2);
    const float* q0_12 = s0 + R(i + 1, j + 2);
    f2 s0_12a = *(const f2*)q0_12;  float s0_12_2 = q0_12[2];
    const float* q0_10 = s0 + R(i + 1, j);
    float s0_10_1 = q0_10[1];       f2 s0_10b = *(const f2*)(q0_10 + 2);

    float s2_21_1 = s2[R(i + 2, j + 1) + 1], s2_21_2 = s2[R(i + 2, j + 1) + 2];
    float s2_11_1 = s2[R(i + 1, j + 1) + 1], s2_11_2 = s2[R(i + 1, j + 1) + 2];
    float s2_20_1 = s2[R(i + 2, j)     + 1], s2_20_2 = s2[R(i + 2, j)     + 2];
    float s2_10_1 = s2[R(i + 1, j)     + 1], s2_10_2 = s2[R(i + 1, j)     + 2];
    float s2_12_1 = s2[R(i + 1, j + 2) + 1], s2_12_2 = s2[R(i + 1, j + 2) + 2];
    float s2_02_1 = s2[R(i,     j + 2) + 1], s2_02_2 = s2[R(i,     j + 2) + 2];
    float s2_01_1 = s2[R(i,     j + 1) + 1], s2_01_2 = s2[R(i,     j + 1) + 2];
#undef R

    // u = d_x s1 - d_y s0 ; mu = (u(t+1)+u(t))/2
    float u0 = (s1_21a.x - s1_11a.x) - (s0_12a.x - s0_11a.x);
    float u1 = (s1_21a.y - s1_11a.y) - (s0_12a.y - s0_11a.y);
    float u2 = (s1_21_2  - s1_11b.x) - (s0_12_2  - s0_11b.x);
    float mus0 = (u1 + u0) * 0.5f;
    float mus1 = (u2 + u1) * 0.5f;

    // v = d_t s0 - d_x s2 ; mv = (v(j+1)+v(j))/2
    float v1_0 = (s0_11b.x - s0_11a.y) - (s2_21_1 - s2_11_1);
    float v0_0 = (s0_10b.x - s0_10_1)  - (s2_20_1 - s2_10_1);
    float mvs0 = (v1_0 + v0_0) * 0.5f;
    float v1_1 = (s0_11b.y - s0_11b.x) - (s2_21_2 - s2_11_2);
    float v0_1 = (s0_10b.y - s0_10b.x) - (s2_20_2 - s2_10_2);
    float mvs1 = (v1_1 + v0_1) * 0.5f;

    // w = d_y s2 - d_t s1 ; mw = (w(i+1)+w(i))/2
    float w1_0 = (s2_12_1 - s2_11_1) - (s1_11b.x - s1_11a.y);
    float w0_0 = (s2_02_1 - s2_01_1) - (s1_01b.x - s1_01_1);
    float mws0 = (w1_0 + w0_0) * 0.5f;
    float w1_1 = (s2_12_2 - s2_11_2) - (s1_11b.y - s1_11b.x);
    float w0_1 = (s2_02_2 - s2_01_2) - (s1_01b.y - s1_01b.x);
    float mws1 = (w1_1 + w0_1) * 0.5f;

    const size_t oc = (size_t)O * O * O;
    const size_t o  = ((size_t)i * O + j) * O + t;
    const size_t b3 = (size_t)b * 3;
    __builtin_nontemporal_store(f2{mup0, mup1}, (f2*)(vphi + (b3 + 0) * oc + o));
    __builtin_nontemporal_store(f2{mvp0, mvp1}, (f2*)(vphi + (b3 + 1) * oc + o));
    __builtin_nontemporal_store(f2{mwp0, mwp1}, (f2*)(vphi + (b3 + 2) * oc + o));
    __builtin_nontemporal_store(f2{mus0, mus1}, (f2*)(vstr + (b3 + 0) * oc + o));
    __builtin_nontemporal_store(f2{mvs0, mvs1}, (f2*)(vstr + (b3 + 1) * oc + o));
    __builtin_nontemporal_store(f2{mws0, mws1}, (f2*)(vstr + (b3 + 2) * oc + o));
    __builtin_nontemporal_store(f2{mup0 + mus0, mup1 + mus1}, (f2*)(vel + (b3 + 0) * oc + o));
    __builtin_nontemporal_store(f2{mvp0 + mvs0, mvp1 + mvs1}, (f2*)(vel + (b3 + 1) * oc + o));
    __builtin_nontemporal_store(f2{mwp0 + mws0, mwp1 + mws1}, (f2*)(vel + (b3 + 2) * oc + o));
}

__global__ __launch_bounds__(256) void fused_kernel(
    const float* __restrict__ prev, const float* __restrict__ nxt,
    const float* __restrict__ phi, const float* __restrict__ stm,
    float* __restrict__ corr, float* __restrict__ vel,
    float* __restrict__ vphi, float* __restrict__ vstr)
{
    int bid = blockIdx.x;
    if (bid < CORR_NWG) {
        corr_body(bid, prev, nxt, corr);
    } else {
        vel_body(bid - CORR_NWG, phi, stm, vel, vphi, vstr);
    }
}

extern "C" void kernel_launch(void* const* d_in, const int* in_sizes, int n_in,
                              void* d_out, int out_size, void* d_ws, size_t ws_size,
                              hipStream_t stream)
{
    const float* prev = (const float*)d_in[0];
    const float* nxt  = (const float*)d_in[1];
    const float* phi  = (const float*)d_in[2];
    const float* stm  = (const float*)d_in[3];

    float* out = (float*)d_out;
    const size_t corr_sz = (size_t)CB * 27 * CX * CY * CZ;   // 23,887,872
    const size_t vel_sz  = (size_t)CB * 3 * O * O * O;       // 19,934,016
    float* corr = out;
    float* vel  = out + corr_sz;
    float* vphi = vel + vel_sz;
    float* vstr = vphi + vel_sz;

    fused_kernel<<<CORR_NWG + VEL_NWG, 256, 0, stream>>>(
        prev, nxt, phi, stm, corr, vel, vphi, vstr);
}